// Round 10
// baseline (54.260 us; speedup 1.0000x reference)
//
#include <hip/hip_runtime.h>
#include <math.h>

#define KC     10      // clusters
#define BLOCK  256
#define WPB    4       // waves per block
#define NQ     (3*KC)  // pos[10], neg[10], cnt[10]
#define NBLK   1024    // blocks; co-resident (16 waves/CU @ VGPR~128)
#define SCALE  16777216.0f   // 2^24 fixed-point scale for pos/neg

typedef float v2f __attribute__((ext_vector_type(2)));
union F4 { float4 f; v2f h[2]; };

// 4-lane (quad) allreduce-add via DPP quad_perm — VALU, not DS pipe.
__device__ __forceinline__ float quad_allreduce_add(float x) {
    int y = __builtin_amdgcn_update_dpp(0, __float_as_int(x), 0xB1, 0xF, 0xF, true);
    x += __int_as_float(y);
    y = __builtin_amdgcn_update_dpp(0, __float_as_int(x), 0x4E, 0xF, 0xF, true);
    return x + __int_as_float(y);
}

// ---------------------------------------------------------------------------
// Single fused kernel. Main loop = round-6 structure (best measured).
// Cross-block reduction via DEVICE-SCOPE u64 ATOMICS in fixed point:
//   - integer addition commutes -> final sums bit-deterministic regardless
//     of block arrival order (no float-atomic nondeterminism);
//   - atomics go to the coherent point directly -> NO __threadfence
//     (round 7 showed per-block threadfence = ~1us L2-walk each, +100us).
// acc layout in ws: u64 acc[30] (pos*2^24 [0..9], neg*2^24 [10..19],
// cnt [20..29]), u32 counter at byte 240. Host zeroes bytes [0,256) per
// call via hipMemsetAsync (graph-capturable). Last block (counter) reads
// the 30 sums via atomicAdd(..,0) and computes the loss in fixed order.
// NO __launch_bounds__ min-waves arg (rounds 1/2/4: forces spill).
// ---------------------------------------------------------------------------
__global__ __launch_bounds__(BLOCK) void cl_fused(
    const float* __restrict__ feat, const int* __restrict__ pred,
    const float* __restrict__ centers,
    unsigned long long* __restrict__ acc,      // 30 u64
    unsigned* __restrict__ counter,            // 1 u32
    float* __restrict__ out,
    int N, int nWaves, int nBlocks)
{
    __shared__ float4 c_lds[KC * 16];   // 2.5 KB
    __shared__ float  blk[WPB][NQ];
    __shared__ int    isLast;
    __shared__ float  sq[NQ];

    const int tid = threadIdx.x;
    if (tid < KC * 16)
        c_lds[tid] = ((const float4*)centers)[tid];
    __syncthreads();

    const int lane = tid & 63;
    const int wave = tid >> 6;
    const int wgid = blockIdx.x * WPB + wave;
    const int s4   = lane & 3;
    const int g    = lane >> 2;

    float pos0=0.f,pos1=0.f,pos2=0.f, neg0=0.f,neg1=0.f,neg2=0.f,
          cnt0=0.f,cnt1=0.f,cnt2=0.f;

    const int nTiles = (N + 31) >> 5;           // 32 rows per tile
    for (int t = wgid; t < nTiles; t += nWaves) {
        const int rowA = (t << 5) + g;
        const int rowB = rowA + 16;
        const int rcA  = rowA < N ? rowA : N - 1;
        const int rcB  = rowB < N ? rowB : N - 1;
        const float4* rpA = (const float4*)feat + (size_t)rcA * 16 + s4;
        const float4* rpB = (const float4*)feat + (size_t)rcB * 16 + s4;
        F4 a0,a1,a2,a3, b0,b1,b2,b3;
        a0.f = rpA[0]; a1.f = rpA[4]; a2.f = rpA[8]; a3.f = rpA[12];
        b0.f = rpB[0]; b1.f = rpB[4]; b2.f = rpB[8]; b3.f = rpB[12];
        const int   pA = pred[rcA], pB = pred[rcB];
        const float actA = rowA < N ? 1.f : 0.f;
        const float actB = rowB < N ? 1.f : 0.f;

        float dA0=0.f,dA1=0.f,dA2=0.f, dB0=0.f,dB1=0.f,dB2=0.f;
#pragma unroll
        for (int k = 0; k < KC; ++k) {
            F4 c0,c1,c2,c3;
            c0.f = c_lds[k*16 + 0  + s4];
            c1.f = c_lds[k*16 + 4  + s4];
            c2.f = c_lds[k*16 + 8  + s4];
            c3.f = c_lds[k*16 + 12 + s4];
            v2f sA = a0.h[0]*c0.h[0]; sA += a0.h[1]*c0.h[1];
            sA += a1.h[0]*c1.h[0];    sA += a1.h[1]*c1.h[1];
            sA += a2.h[0]*c2.h[0];    sA += a2.h[1]*c2.h[1];
            sA += a3.h[0]*c3.h[0];    sA += a3.h[1]*c3.h[1];
            v2f sB = b0.h[0]*c0.h[0]; sB += b0.h[1]*c0.h[1];
            sB += b1.h[0]*c1.h[0];    sB += b1.h[1]*c1.h[1];
            sB += b2.h[0]*c2.h[0];    sB += b2.h[1]*c2.h[1];
            sB += b3.h[0]*c3.h[0];    sB += b3.h[1]*c3.h[1];
            const float dkA = quad_allreduce_add(sA.x + sA.y);
            const float dkB = quad_allreduce_add(sB.x + sB.y);
            const bool own = (s4 == (k & 3));   // unique owner per quad
            if ((k >> 2) == 0)      { dA0 = own ? dkA : dA0; dB0 = own ? dkB : dB0; }
            else if ((k >> 2) == 1) { dA1 = own ? dkA : dA1; dB1 = own ? dkB : dB1; }
            else                    { dA2 = own ? dkA : dA2; dB2 = own ? dkB : dB2; }
        }
        const float m2A = (s4 < 2) ? actA : 0.f;    // slot2 real only for s4<2
        const float m2B = (s4 < 2) ? actB : 0.f;
        {   // row A epilogue: owned clusters k = s4, s4+4, s4+8
            float e = __expf(fminf(fmaxf(dA0*0.5f,-10.f),10.f)) * actA;
            bool h = (pA == s4);      neg0 += e; pos0 += h?e:0.f; cnt0 += h?actA:0.f;
            e = __expf(fminf(fmaxf(dA1*0.5f,-10.f),10.f)) * actA;
            h = (pA == s4+4);         neg1 += e; pos1 += h?e:0.f; cnt1 += h?actA:0.f;
            e = __expf(fminf(fmaxf(dA2*0.5f,-10.f),10.f)) * m2A;
            h = (pA == s4+8);         neg2 += e; pos2 += h?e:0.f; cnt2 += h?m2A:0.f;
        }
        {   // row B epilogue
            float e = __expf(fminf(fmaxf(dB0*0.5f,-10.f),10.f)) * actB;
            bool h = (pB == s4);      neg0 += e; pos0 += h?e:0.f; cnt0 += h?actB:0.f;
            e = __expf(fminf(fmaxf(dB1*0.5f,-10.f),10.f)) * actB;
            h = (pB == s4+4);         neg1 += e; pos1 += h?e:0.f; cnt1 += h?actB:0.f;
            e = __expf(fminf(fmaxf(dB2*0.5f,-10.f),10.f)) * m2B;
            h = (pB == s4+8);         neg2 += e; pos2 += h?e:0.f; cnt2 += h?m2B:0.f;
        }
    }

    // reduce across the 16 lanes sharing this s4 (one-time)
#pragma unroll
    for (int off = 4; off <= 32; off <<= 1) {
        pos0 += __shfl_xor(pos0, off, 64); neg0 += __shfl_xor(neg0, off, 64); cnt0 += __shfl_xor(cnt0, off, 64);
        pos1 += __shfl_xor(pos1, off, 64); neg1 += __shfl_xor(neg1, off, 64); cnt1 += __shfl_xor(cnt1, off, 64);
        pos2 += __shfl_xor(pos2, off, 64); neg2 += __shfl_xor(neg2, off, 64); cnt2 += __shfl_xor(cnt2, off, 64);
    }

    if (lane < 4) {             // lane == s4
        const int k0 = lane, k1 = lane + 4, k2 = lane + 8;
        blk[wave][k0] = pos0; blk[wave][KC + k0] = neg0; blk[wave][2*KC + k0] = cnt0;
        blk[wave][k1] = pos1; blk[wave][KC + k1] = neg1; blk[wave][2*KC + k1] = cnt1;
        if (k2 < KC) {
            blk[wave][k2] = pos2; blk[wave][KC + k2] = neg2; blk[wave][2*KC + k2] = cnt2;
        }
    }
    __syncthreads();

    // ---- block partial -> deterministic fixed-point u64 atomics ----
    if (tid < NQ) {
        const float s = blk[0][tid] + blk[1][tid] + blk[2][tid] + blk[3][tid];
        const float scaled = (tid < 2 * KC) ? (s * SCALE) : s;   // cnt plain
        atomicAdd(&acc[tid], (unsigned long long)(scaled + 0.5f));
    }
    // order: data atomics (wave 0) must complete before counter atomic
    asm volatile("s_waitcnt vmcnt(0)" ::: "memory");
    if (tid == 0) {
        const unsigned old = atomicAdd(counter, 1u);
        isLast = (old == (unsigned)(nBlocks - 1)) ? 1 : 0;
    }
    __syncthreads();
    if (!isLast) return;

    // ---- last block: coherent atomic reads, fixed-order loss ----
    if (tid < NQ) {
        const unsigned long long v = atomicAdd(&acc[tid], 0ULL);
        sq[tid] = (tid < 2 * KC) ? (float)((double)v / (double)SCALE)
                                 : (float)v;
    }
    __syncthreads();
    if (tid == 0) {
        float tot = 0.f;
        int nv = 0;
#pragma unroll
        for (int k = 0; k < KC; ++k) {
            const float pos_s = sq[k];
            const float neg_s = sq[KC + k];
            const float cnt   = sq[2 * KC + k];
            const float neg = neg_s / (float)N;             // e.mean(axis=0)
            const float pos = pos_s / fmaxf(cnt, 1.f);      // sum / max(count,1)
            const float lt  = -logf(pos / (neg + 1e-8f));
            const bool valid = (cnt > 0.f) && (cnt < (float)N) &&
                               (pos > 1e-8f) && (neg > 1e-8f) && isfinite(lt);
            if (valid) { tot += lt; ++nv; }
        }
        out[0] = (nv > 0 ? tot / (float)nv : 0.f) * 5.0f;   // * weight
    }
}

extern "C" void kernel_launch(void* const* d_in, const int* in_sizes, int n_in,
                              void* d_out, int out_size, void* d_ws, size_t ws_size,
                              hipStream_t stream) {
    const float* feat    = (const float*)d_in[0];
    const int*   pred    = (const int*)d_in[1];
    const float* centers = (const float*)d_in[2];
    float*       out     = (float*)d_out;
    const int N = in_sizes[1];          // 500000

    // ws: u64 acc[30] at byte 0, u32 counter at byte 240; zero [0,256)
    unsigned long long* acc = (unsigned long long*)d_ws;
    unsigned* counter = (unsigned*)((char*)d_ws + 240);

    const int nBlocks = NBLK;
    const int nWaves  = nBlocks * WPB;

    hipMemsetAsync(d_ws, 0, 256, stream);
    hipLaunchKernelGGL(cl_fused, dim3(nBlocks), dim3(BLOCK), 0, stream,
                       feat, pred, centers, acc, counter, out,
                       N, nWaves, nBlocks);
}

// Round 11
// 37.820 us; speedup vs baseline: 1.4347x; 1.4347x over previous
//
#include <hip/hip_runtime.h>
#include <math.h>

#define KC     10      // clusters
#define BLOCK  256
#define WPB    4       // waves per block
#define NQ     (3*KC)  // pos[10], neg[10], cnt[10]
#define NBLK   1024    // blocks; co-resident (16 waves/CU @ VGPR 128)
#define BLOCKF 512     // finalize threads

typedef float v2f __attribute__((ext_vector_type(2)));
union F4 { float4 f; v2f h[2]; };

// 4-lane (quad) allreduce-add via DPP quad_perm — VALU, not DS pipe.
__device__ __forceinline__ float quad_allreduce_add(float x) {
    int y = __builtin_amdgcn_update_dpp(0, __float_as_int(x), 0xB1, 0xF, 0xF, true);
    x += __int_as_float(y);
    y = __builtin_amdgcn_update_dpp(0, __float_as_int(x), 0x4E, 0xF, 0xF, true);
    return x + __int_as_float(y);
}

// ---------------------------------------------------------------------------
// Main kernel = round-6/8 structure (best measured, 35.7/36.2us) + explicit
// ONE-DEEP REGISTER PREFETCH: loads for tile t+nWaves issue before compute
// of tile t (compiler won't pipeline the back-edge itself; r6/8 profile is
// latency-bound: VALUBusy 5%, DS ~12us, HBM not saturated).
// __launch_bounds__(256,2) pins the VGPR cap at 128 (measured r1); live set
// ~111 fits -> no spill (falsifier: WRITE_SIZE balloon).
// Two-kernel reduction ON PURPOSE: fused alternatives measured WORSE
// (r7 threadfence: +100us L2 walks; r10 u64-atomic train: +18us).
// ---------------------------------------------------------------------------
__global__ __launch_bounds__(BLOCK, 2) void cl_main(
    const float* __restrict__ feat, const int* __restrict__ pred,
    const float* __restrict__ centers, float* __restrict__ ws,
    int N, int nWaves, int nBlocks)
{
    __shared__ float4 c_lds[KC * 16];   // 2.5 KB
    __shared__ float  blk[WPB][NQ];
    const int tid = threadIdx.x;
    if (tid < KC * 16)
        c_lds[tid] = ((const float4*)centers)[tid];
    __syncthreads();

    const int lane = tid & 63;
    const int wave = tid >> 6;
    const int wgid = blockIdx.x * WPB + wave;
    const int s4   = lane & 3;
    const int g    = lane >> 2;

    float pos0=0.f,pos1=0.f,pos2=0.f, neg0=0.f,neg1=0.f,neg2=0.f,
          cnt0=0.f,cnt1=0.f,cnt2=0.f;

    const int nTiles = (N + 31) >> 5;           // 32 rows per tile

    // ---- preload tile t0 ----
    int t = wgid;
    bool have = (t < nTiles);
    F4 a0,a1,a2,a3, b0,b1,b2,b3;
    int pA = 0, pB = 0;
    if (have) {
        const int rowA = (t << 5) + g;
        const int rowB = rowA + 16;
        const int rcA  = rowA < N ? rowA : N - 1;
        const int rcB  = rowB < N ? rowB : N - 1;
        const float4* rpA = (const float4*)feat + (size_t)rcA * 16 + s4;
        const float4* rpB = (const float4*)feat + (size_t)rcB * 16 + s4;
        a0.f = rpA[0]; a1.f = rpA[4]; a2.f = rpA[8]; a3.f = rpA[12];
        b0.f = rpB[0]; b1.f = rpB[4]; b2.f = rpB[8]; b3.f = rpB[12];
        pA = pred[rcA]; pB = pred[rcB];
    }

    while (have) {
        // ---- issue prefetch for t+nWaves (hides HBM latency under compute) ----
        const int tn = t + nWaves;
        const bool haveN = (tn < nTiles);
        F4 na0,na1,na2,na3, nb0,nb1,nb2,nb3;
        int npA = 0, npB = 0;
        if (haveN) {
            const int rowA = (tn << 5) + g;
            const int rowB = rowA + 16;
            const int rcA  = rowA < N ? rowA : N - 1;
            const int rcB  = rowB < N ? rowB : N - 1;
            const float4* rpA = (const float4*)feat + (size_t)rcA * 16 + s4;
            const float4* rpB = (const float4*)feat + (size_t)rcB * 16 + s4;
            na0.f = rpA[0]; na1.f = rpA[4]; na2.f = rpA[8]; na3.f = rpA[12];
            nb0.f = rpB[0]; nb1.f = rpB[4]; nb2.f = rpB[8]; nb3.f = rpB[12];
            npA = pred[rcA]; npB = pred[rcB];
        }

        // ---- compute current tile (round-6 k-loop, unchanged) ----
        const int rowA = (t << 5) + g;
        const int rowB = rowA + 16;
        const float actA = rowA < N ? 1.f : 0.f;
        const float actB = rowB < N ? 1.f : 0.f;

        float dA0=0.f,dA1=0.f,dA2=0.f, dB0=0.f,dB1=0.f,dB2=0.f;
#pragma unroll
        for (int k = 0; k < KC; ++k) {
            F4 c0,c1,c2,c3;
            c0.f = c_lds[k*16 + 0  + s4];
            c1.f = c_lds[k*16 + 4  + s4];
            c2.f = c_lds[k*16 + 8  + s4];
            c3.f = c_lds[k*16 + 12 + s4];
            v2f sA = a0.h[0]*c0.h[0]; sA += a0.h[1]*c0.h[1];
            sA += a1.h[0]*c1.h[0];    sA += a1.h[1]*c1.h[1];
            sA += a2.h[0]*c2.h[0];    sA += a2.h[1]*c2.h[1];
            sA += a3.h[0]*c3.h[0];    sA += a3.h[1]*c3.h[1];
            v2f sB = b0.h[0]*c0.h[0]; sB += b0.h[1]*c0.h[1];
            sB += b1.h[0]*c1.h[0];    sB += b1.h[1]*c1.h[1];
            sB += b2.h[0]*c2.h[0];    sB += b2.h[1]*c2.h[1];
            sB += b3.h[0]*c3.h[0];    sB += b3.h[1]*c3.h[1];
            const float dkA = quad_allreduce_add(sA.x + sA.y);
            const float dkB = quad_allreduce_add(sB.x + sB.y);
            const bool own = (s4 == (k & 3));   // unique owner per quad
            if ((k >> 2) == 0)      { dA0 = own ? dkA : dA0; dB0 = own ? dkB : dB0; }
            else if ((k >> 2) == 1) { dA1 = own ? dkA : dA1; dB1 = own ? dkB : dB1; }
            else                    { dA2 = own ? dkA : dA2; dB2 = own ? dkB : dB2; }
        }
        const float m2A = (s4 < 2) ? actA : 0.f;    // slot2 real only for s4<2
        const float m2B = (s4 < 2) ? actB : 0.f;
        {   // row A epilogue: owned clusters k = s4, s4+4, s4+8
            float e = __expf(fminf(fmaxf(dA0*0.5f,-10.f),10.f)) * actA;
            bool h = (pA == s4);      neg0 += e; pos0 += h?e:0.f; cnt0 += h?actA:0.f;
            e = __expf(fminf(fmaxf(dA1*0.5f,-10.f),10.f)) * actA;
            h = (pA == s4+4);         neg1 += e; pos1 += h?e:0.f; cnt1 += h?actA:0.f;
            e = __expf(fminf(fmaxf(dA2*0.5f,-10.f),10.f)) * m2A;
            h = (pA == s4+8);         neg2 += e; pos2 += h?e:0.f; cnt2 += h?m2A:0.f;
        }
        {   // row B epilogue
            float e = __expf(fminf(fmaxf(dB0*0.5f,-10.f),10.f)) * actB;
            bool h = (pB == s4);      neg0 += e; pos0 += h?e:0.f; cnt0 += h?actB:0.f;
            e = __expf(fminf(fmaxf(dB1*0.5f,-10.f),10.f)) * actB;
            h = (pB == s4+4);         neg1 += e; pos1 += h?e:0.f; cnt1 += h?actB:0.f;
            e = __expf(fminf(fmaxf(dB2*0.5f,-10.f),10.f)) * m2B;
            h = (pB == s4+8);         neg2 += e; pos2 += h?e:0.f; cnt2 += h?m2B:0.f;
        }

        // ---- rotate ----
        t = tn; have = haveN;
        a0 = na0; a1 = na1; a2 = na2; a3 = na3;
        b0 = nb0; b1 = nb1; b2 = nb2; b3 = nb3;
        pA = npA; pB = npB;
    }

    // reduce across the 16 lanes sharing this s4 (one-time)
#pragma unroll
    for (int off = 4; off <= 32; off <<= 1) {
        pos0 += __shfl_xor(pos0, off, 64); neg0 += __shfl_xor(neg0, off, 64); cnt0 += __shfl_xor(cnt0, off, 64);
        pos1 += __shfl_xor(pos1, off, 64); neg1 += __shfl_xor(neg1, off, 64); cnt1 += __shfl_xor(cnt1, off, 64);
        pos2 += __shfl_xor(pos2, off, 64); neg2 += __shfl_xor(neg2, off, 64); cnt2 += __shfl_xor(cnt2, off, 64);
    }

    if (lane < 4) {             // lane == s4
        const int k0 = lane, k1 = lane + 4, k2 = lane + 8;
        blk[wave][k0] = pos0; blk[wave][KC + k0] = neg0; blk[wave][2*KC + k0] = cnt0;
        blk[wave][k1] = pos1; blk[wave][KC + k1] = neg1; blk[wave][2*KC + k1] = cnt1;
        if (k2 < KC) {
            blk[wave][k2] = pos2; blk[wave][KC + k2] = neg2; blk[wave][2*KC + k2] = cnt2;
        }
    }
    __syncthreads();
    if (tid < NQ) {             // block partial, layout [q][nBlocks]
        const float s = blk[0][tid] + blk[1][tid] + blk[2][tid] + blk[3][tid];
        ws[(size_t)tid * nBlocks + blockIdx.x] = s;
    }
}

// ---------------------------------------------------------------------------
// Finalize: one 512-thread block; 16-thread group per quantity (30 groups),
// float4 coalesced reads, fixed-order butterfly, thread 0 computes the loss.
// ---------------------------------------------------------------------------
__global__ __launch_bounds__(BLOCKF) void cl_final(
    const float* __restrict__ ws, float* __restrict__ out, int N, int nBlocks)
{
    const int tid = threadIdx.x;
    const int grp = tid >> 4, sub = tid & 15;   // 16 threads per quantity
    __shared__ float sq[NQ];

    float acc = 0.f;
    if (grp < NQ) {
        const float4* w4 = (const float4*)(ws + (size_t)grp * nBlocks);
        const int n4 = nBlocks >> 2;
        for (int i = sub; i < n4; i += 16) {
            const float4 v = w4[i];
            acc += (v.x + v.y) + (v.z + v.w);
        }
    }
    acc += __shfl_xor(acc, 1, 64);
    acc += __shfl_xor(acc, 2, 64);
    acc += __shfl_xor(acc, 4, 64);
    acc += __shfl_xor(acc, 8, 64);
    if (grp < NQ && sub == 0) sq[grp] = acc;
    __syncthreads();

    if (tid == 0) {
        float tot = 0.f;
        int nv = 0;
#pragma unroll
        for (int k = 0; k < KC; ++k) {
            const float pos_s = sq[k];
            const float neg_s = sq[KC + k];
            const float cnt   = sq[2 * KC + k];
            const float neg = neg_s / (float)N;             // e.mean(axis=0)
            const float pos = pos_s / fmaxf(cnt, 1.f);      // sum / max(count,1)
            const float lt  = -logf(pos / (neg + 1e-8f));
            const bool valid = (cnt > 0.f) && (cnt < (float)N) &&
                               (pos > 1e-8f) && (neg > 1e-8f) && isfinite(lt);
            if (valid) { tot += lt; ++nv; }
        }
        out[0] = (nv > 0 ? tot / (float)nv : 0.f) * 5.0f;   // * weight
    }
}

extern "C" void kernel_launch(void* const* d_in, const int* in_sizes, int n_in,
                              void* d_out, int out_size, void* d_ws, size_t ws_size,
                              hipStream_t stream) {
    const float* feat    = (const float*)d_in[0];
    const int*   pred    = (const int*)d_in[1];
    const float* centers = (const float*)d_in[2];
    float*       out     = (float*)d_out;
    const int N = in_sizes[1];          // 500000

    int nBlocks = NBLK;
    const int maxB = (int)(ws_size / (NQ * sizeof(float)));
    if (nBlocks > maxB) nBlocks = maxB & ~3;
    if (nBlocks < 4) nBlocks = 4;
    const int nWaves = nBlocks * WPB;

    hipLaunchKernelGGL(cl_main, dim3(nBlocks), dim3(BLOCK), 0, stream,
                       feat, pred, centers, (float*)d_ws, N, nWaves, nBlocks);
    hipLaunchKernelGGL(cl_final, dim3(1), dim3(BLOCKF), 0, stream,
                       (const float*)d_ws, out, N, nBlocks);
}

// Round 12
// 35.855 us; speedup vs baseline: 1.5133x; 1.0548x over previous
//
#include <hip/hip_runtime.h>
#include <math.h>

#define KC     10      // clusters
#define BLOCK  256
#define WPB    4       // waves per block
#define NQ     (3*KC)  // pos[10], neg[10], cnt[10]
#define NBLK   2048    // main-kernel blocks; ws partials = one per block
#define BLOCKF 1024    // finalize threads

typedef float v2f __attribute__((ext_vector_type(2)));
union F4 { float4 f; v2f h[2]; };

// 4-lane (quad) allreduce-add via DPP quad_perm — VALU, not DS pipe.
// 0xB1 = quad_perm[1,0,3,2] (xor 1), 0x4E = quad_perm[2,3,0,1] (xor 2).
__device__ __forceinline__ float quad_allreduce_add(float x) {
    int y = __builtin_amdgcn_update_dpp(0, __float_as_int(x), 0xB1, 0xF, 0xF, true);
    x += __int_as_float(y);
    y = __builtin_amdgcn_update_dpp(0, __float_as_int(x), 0x4E, 0xF, 0xF, true);
    return x + __int_as_float(y);
}

// ---------------------------------------------------------------------------
// FINAL KERNEL — round-6 structure, best measured (35.7 us).
// Session-verified design decisions (each alternative measured WORSE):
//  - 2 rows/lane, quad-split columns, direct global float4 loads (LDS
//    staging r9: 38.3; register prefetch r11: 37.8).
//  - DPP quad-reduce on VALU pipe (shfl/ds_bpermute version r5: 57).
//  - Owned-cluster epilogue: 6 exps/lane/iter via static cndmask.
//  - Two-kernel reduction at a kernel boundary (fused threadfence r7:
//    138; fused u64-atomic train r10: 54).
//  - NO __launch_bounds__ min-waves arg (r1/2/4: hipcc caps VGPRs at
//    ~half the formula -> scratch spill, GB-scale WRITE_SIZE).
// ---------------------------------------------------------------------------
__global__ __launch_bounds__(BLOCK) void cl_main(
    const float* __restrict__ feat, const int* __restrict__ pred,
    const float* __restrict__ centers, float* __restrict__ ws,
    int N, int nWaves, int nBlocks)
{
    __shared__ float4 c_lds[KC * 16];   // 2.5 KB
    __shared__ float  blk[WPB][NQ];
    const int tid = threadIdx.x;
    if (tid < KC * 16)
        c_lds[tid] = ((const float4*)centers)[tid];
    __syncthreads();

    const int lane = tid & 63;
    const int wave = tid >> 6;
    const int wgid = blockIdx.x * WPB + wave;
    const int s4   = lane & 3;
    const int g    = lane >> 2;

    float pos0=0.f,pos1=0.f,pos2=0.f, neg0=0.f,neg1=0.f,neg2=0.f,
          cnt0=0.f,cnt1=0.f,cnt2=0.f;

    const int nTiles = (N + 31) >> 5;           // 32 rows per tile
    for (int t = wgid; t < nTiles; t += nWaves) {
        const int rowA = (t << 5) + g;
        const int rowB = rowA + 16;
        const int rcA  = rowA < N ? rowA : N - 1;
        const int rcB  = rowB < N ? rowB : N - 1;
        const float4* rpA = (const float4*)feat + (size_t)rcA * 16 + s4;
        const float4* rpB = (const float4*)feat + (size_t)rcB * 16 + s4;
        F4 a0,a1,a2,a3, b0,b1,b2,b3;
        a0.f = rpA[0]; a1.f = rpA[4]; a2.f = rpA[8]; a3.f = rpA[12];
        b0.f = rpB[0]; b1.f = rpB[4]; b2.f = rpB[8]; b3.f = rpB[12];
        const int   pA = pred[rcA], pB = pred[rcB];
        const float actA = rowA < N ? 1.f : 0.f;
        const float actB = rowB < N ? 1.f : 0.f;

        float dA0=0.f,dA1=0.f,dA2=0.f, dB0=0.f,dB1=0.f,dB2=0.f;
#pragma unroll
        for (int k = 0; k < KC; ++k) {
            F4 c0,c1,c2,c3;
            c0.f = c_lds[k*16 + 0  + s4];
            c1.f = c_lds[k*16 + 4  + s4];
            c2.f = c_lds[k*16 + 8  + s4];
            c3.f = c_lds[k*16 + 12 + s4];
            v2f sA = a0.h[0]*c0.h[0]; sA += a0.h[1]*c0.h[1];
            sA += a1.h[0]*c1.h[0];    sA += a1.h[1]*c1.h[1];
            sA += a2.h[0]*c2.h[0];    sA += a2.h[1]*c2.h[1];
            sA += a3.h[0]*c3.h[0];    sA += a3.h[1]*c3.h[1];
            v2f sB = b0.h[0]*c0.h[0]; sB += b0.h[1]*c0.h[1];
            sB += b1.h[0]*c1.h[0];    sB += b1.h[1]*c1.h[1];
            sB += b2.h[0]*c2.h[0];    sB += b2.h[1]*c2.h[1];
            sB += b3.h[0]*c3.h[0];    sB += b3.h[1]*c3.h[1];
            const float dkA = quad_allreduce_add(sA.x + sA.y);
            const float dkB = quad_allreduce_add(sB.x + sB.y);
            const bool own = (s4 == (k & 3));   // unique owner per quad
            if ((k >> 2) == 0)      { dA0 = own ? dkA : dA0; dB0 = own ? dkB : dB0; }
            else if ((k >> 2) == 1) { dA1 = own ? dkA : dA1; dB1 = own ? dkB : dB1; }
            else                    { dA2 = own ? dkA : dA2; dB2 = own ? dkB : dB2; }
        }
        const float m2A = (s4 < 2) ? actA : 0.f;    // slot2 real only for s4<2
        const float m2B = (s4 < 2) ? actB : 0.f;
        {   // row A epilogue: owned clusters k = s4, s4+4, s4+8
            float e = __expf(fminf(fmaxf(dA0*0.5f,-10.f),10.f)) * actA;
            bool h = (pA == s4);      neg0 += e; pos0 += h?e:0.f; cnt0 += h?actA:0.f;
            e = __expf(fminf(fmaxf(dA1*0.5f,-10.f),10.f)) * actA;
            h = (pA == s4+4);         neg1 += e; pos1 += h?e:0.f; cnt1 += h?actA:0.f;
            e = __expf(fminf(fmaxf(dA2*0.5f,-10.f),10.f)) * m2A;
            h = (pA == s4+8);         neg2 += e; pos2 += h?e:0.f; cnt2 += h?m2A:0.f;
        }
        {   // row B epilogue
            float e = __expf(fminf(fmaxf(dB0*0.5f,-10.f),10.f)) * actB;
            bool h = (pB == s4);      neg0 += e; pos0 += h?e:0.f; cnt0 += h?actB:0.f;
            e = __expf(fminf(fmaxf(dB1*0.5f,-10.f),10.f)) * actB;
            h = (pB == s4+4);         neg1 += e; pos1 += h?e:0.f; cnt1 += h?actB:0.f;
            e = __expf(fminf(fmaxf(dB2*0.5f,-10.f),10.f)) * m2B;
            h = (pB == s4+8);         neg2 += e; pos2 += h?e:0.f; cnt2 += h?m2B:0.f;
        }
    }

    // reduce across the 16 lanes sharing this s4 (one-time; shfl fine here)
#pragma unroll
    for (int off = 4; off <= 32; off <<= 1) {
        pos0 += __shfl_xor(pos0, off, 64); neg0 += __shfl_xor(neg0, off, 64); cnt0 += __shfl_xor(cnt0, off, 64);
        pos1 += __shfl_xor(pos1, off, 64); neg1 += __shfl_xor(neg1, off, 64); cnt1 += __shfl_xor(cnt1, off, 64);
        pos2 += __shfl_xor(pos2, off, 64); neg2 += __shfl_xor(neg2, off, 64); cnt2 += __shfl_xor(cnt2, off, 64);
    }

    if (lane < 4) {             // lane == s4
        const int k0 = lane, k1 = lane + 4, k2 = lane + 8;
        blk[wave][k0] = pos0; blk[wave][KC + k0] = neg0; blk[wave][2*KC + k0] = cnt0;
        blk[wave][k1] = pos1; blk[wave][KC + k1] = neg1; blk[wave][2*KC + k1] = cnt1;
        if (k2 < KC) {
            blk[wave][k2] = pos2; blk[wave][KC + k2] = neg2; blk[wave][2*KC + k2] = cnt2;
        }
    }
    __syncthreads();
    if (tid < NQ) {             // block partial, layout [q][nBlocks]
        const float s = blk[0][tid] + blk[1][tid] + blk[2][tid] + blk[3][tid];
        ws[(size_t)tid * nBlocks + blockIdx.x] = s;
    }
}

// ---------------------------------------------------------------------------
// Finalize: 1024 threads; 32-thread group per quantity q (30 active groups),
// float4 coalesced reads, fixed-order butterfly, thread 0 computes the loss.
// ---------------------------------------------------------------------------
__global__ __launch_bounds__(BLOCKF) void cl_final(
    const float* __restrict__ ws, float* __restrict__ out, int N, int nBlocks)
{
    const int tid = threadIdx.x;
    const int grp = tid >> 5, sub = tid & 31;
    __shared__ float sq[NQ];

    float acc = 0.f;
    if (grp < NQ) {
        const float4* w4 = (const float4*)(ws + (size_t)grp * nBlocks);
        const int n4 = nBlocks >> 2;
        for (int i = sub; i < n4; i += 32) {
            const float4 v = w4[i];
            acc += (v.x + v.y) + (v.z + v.w);
        }
    }
#pragma unroll
    for (int off = 1; off <= 16; off <<= 1) acc += __shfl_xor(acc, off, 64);
    if (grp < NQ && sub == 0) sq[grp] = acc;
    __syncthreads();

    if (tid == 0) {
        float tot = 0.f;
        int nv = 0;
#pragma unroll
        for (int k = 0; k < KC; ++k) {
            const float pos_s = sq[k];
            const float neg_s = sq[KC + k];
            const float cnt   = sq[2*KC + k];
            const float neg = neg_s / (float)N;             // e.mean(axis=0)
            const float pos = pos_s / fmaxf(cnt, 1.f);      // sum / max(count,1)
            const float lt  = -logf(pos / (neg + 1e-8f));
            const bool valid = (cnt > 0.f) && (cnt < (float)N) &&
                               (pos > 1e-8f) && (neg > 1e-8f) && isfinite(lt);
            if (valid) { tot += lt; ++nv; }
        }
        out[0] = (nv > 0 ? tot / (float)nv : 0.f) * 5.0f;   // * weight
    }
}

extern "C" void kernel_launch(void* const* d_in, const int* in_sizes, int n_in,
                              void* d_out, int out_size, void* d_ws, size_t ws_size,
                              hipStream_t stream) {
    const float* feat    = (const float*)d_in[0];
    const int*   pred    = (const int*)d_in[1];
    const float* centers = (const float*)d_in[2];
    float*       out     = (float*)d_out;
    const int N = in_sizes[1];          // 500000

    int nBlocks = NBLK;
    const int maxB = (int)(ws_size / (NQ * sizeof(float)));
    if (nBlocks > maxB) nBlocks = maxB & ~3;
    if (nBlocks < 4) nBlocks = 4;
    const int nWaves = nBlocks * WPB;

    hipLaunchKernelGGL(cl_main, dim3(nBlocks), dim3(BLOCK), 0, stream,
                       feat, pred, centers, (float*)d_ws, N, nWaves, nBlocks);
    hipLaunchKernelGGL(cl_final, dim3(1), dim3(BLOCKF), 0, stream,
                       (const float*)d_ws, out, N, nBlocks);
}